// Round 1
// baseline (24.804 us; speedup 1.0000x reference)
//
#include <hip/hip_runtime.h>
#include <hip/hip_bf16.h>
#include <math.h>

// Problem constants (from reference): B=32768, L=24, H=64, V=64
#define B_SZ 32768
#define L_SZ 24
#define H_SZ 64
#define V_SZ 64
#define ROW 68            // padded table row stride in floats (272 B: 16B-aligned, breaks 32-bank alignment)

// Workspace layout (float offsets)
#define HT_OFF 0          // hTab[64][68]
#define WK_OFF 4352       // WkTab[64][68]
#define RN_OFF 8704       // rn[64]
#define B2_OFF 8768       // bias2[64]
#define CF_OFF 8832       // coef[23] = (1 - alpha_t)
#define WS_FLOATS 8864    // = 2216 float4, ~35.4 KB

// ---------------------------------------------------------------------------
// Kernel 1: per-vocab token table. hTab[v] = LN(e + FFN(e)), rn[v] = 1/max(||hTab[v]||, 1e-12)
// grid = 64 (one block per vocab id), block = 128 (= 2H hidden width)
// ---------------------------------------------------------------------------
__global__ __launch_bounds__(128) void k_tables(
    const float* __restrict__ embed, const float* __restrict__ w1, const float* __restrict__ b1,
    const float* __restrict__ w2, const float* __restrict__ b2,
    const float* __restrict__ ln_g, const float* __restrict__ ln_b,
    float* __restrict__ ws)
{
  const int v = blockIdx.x;
  const int tid = threadIdx.x;
  __shared__ float e[H_SZ], hid[2 * H_SZ], x[H_SZ];

  if (tid < H_SZ) e[tid] = embed[v * H_SZ + tid];
  __syncthreads();

  // hidden[j] = relu(e @ w1 + b1), j = 0..127
  float hj = b1[tid];
  #pragma unroll
  for (int h = 0; h < H_SZ; ++h) hj += e[h] * w1[h * (2 * H_SZ) + tid];
  hid[tid] = fmaxf(hj, 0.0f);
  __syncthreads();

  if (tid < H_SZ) {
    float f = b2[tid];
    #pragma unroll
    for (int j = 0; j < 2 * H_SZ; ++j) f += hid[j] * w2[j * H_SZ + tid];
    x[tid] = e[tid] + f;
  }
  __syncthreads();

  if (tid < H_SZ) {           // threads 0..63 = wave 0: wave-wide reductions are safe
    const float xi = x[tid];
    float mu = xi;
    #pragma unroll
    for (int m = 1; m < 64; m <<= 1) mu += __shfl_xor(mu, m);
    mu *= (1.0f / 64.0f);
    const float dv = xi - mu;
    float var = dv * dv;
    #pragma unroll
    for (int m = 1; m < 64; m <<= 1) var += __shfl_xor(var, m);
    var *= (1.0f / 64.0f);
    const float y = dv * rsqrtf(var + 1e-5f) * ln_g[tid] + ln_b[tid];
    ws[HT_OFF + v * ROW + tid] = y;
    float n2 = y * y;
    #pragma unroll
    for (int m = 1; m < 64; m <<= 1) n2 += __shfl_xor(n2, m);
    if (tid == 0) ws[RN_OFF + v] = 1.0f / fmaxf(sqrtf(n2), 1e-12f);
  }
}

// ---------------------------------------------------------------------------
// Kernel 2: WkTab = hTab @ (rp_w @ out_w); bias2 = rp_b @ out_w + out_b; coef[t] = 1 - alpha_t
// grid = 65: blocks 0..63 compute WkTab rows; block 64 computes bias2 + coef. block = 64.
// ---------------------------------------------------------------------------
__global__ __launch_bounds__(64) void k_proj(
    const float* __restrict__ rp_w, const float* __restrict__ rp_b,
    const float* __restrict__ out_w, const float* __restrict__ out_b,
    const float* __restrict__ alpha_logits, float* __restrict__ ws)
{
  const int i = blockIdx.x;
  const int j = threadIdx.x;
  if (i < V_SZ) {
    __shared__ float t1[H_SZ];
    float s = 0.0f;
    #pragma unroll
    for (int k = 0; k < H_SZ; ++k) s += ws[HT_OFF + i * ROW + k] * rp_w[k * H_SZ + j];
    t1[j] = s;
    __syncthreads();
    float s2 = 0.0f;
    #pragma unroll
    for (int k = 0; k < H_SZ; ++k) s2 += t1[k] * out_w[k * V_SZ + j];
    ws[WK_OFF + i * ROW + j] = s2;
  } else {
    float s = out_b[j];
    #pragma unroll
    for (int k = 0; k < H_SZ; ++k) s += rp_b[k] * out_w[k * V_SZ + j];
    ws[B2_OFF + j] = s;
    if (j < L_SZ - 1) {
      const float a = 1.0f / (1.0f + expf(-alpha_logits[j])) * 0.49f + 0.5f;
      ws[CF_OFF + j] = 1.0f - a;
    }
  }
}

// ---------------------------------------------------------------------------
// Kernel 3: main scan. One 4-lane group per batch (16 batches/wave, 64/block).
// Backward recursion over t=22..0:
//   p  = k_tok . qhat            (quad shfl-reduce)
//   d  = p * rn[tok]             (= kn . qhat)
//   c  = (1-a_t) * d
//   out += c * WkTab[tok]
//   qhat -= (c * rn[tok]) * k_tok
// then out += bias2, store.
// ---------------------------------------------------------------------------
__global__ __launch_bounds__(256) void k_scan(
    const int* __restrict__ seq, const float* __restrict__ ws, float* __restrict__ out)
{
  __shared__ float lds[WS_FLOATS];
  const int tid = threadIdx.x;
  // Stage all tables into LDS (L2-resident source; 2216 float4)
  for (int i = tid; i < WS_FLOATS / 4; i += 256)
    ((float4*)lds)[i] = ((const float4*)ws)[i];
  __syncthreads();

  const int lane = tid & 63;
  const int wv = tid >> 6;
  const int g = lane >> 2;          // group (batch) within wave
  const int s = lane & 3;           // 16-element chunk within H
  const int batch = blockIdx.x * 64 + wv * 16 + g;
  const int s16 = s * 16;

  // Per-lane copy of this batch's 24 tokens (group-redundant; 96 B, L2-hit)
  int sqv[L_SZ];
  const int4* sp = (const int4*)(seq + batch * L_SZ);
  #pragma unroll
  for (int i = 0; i < 6; ++i) ((int4*)sqv)[i] = sp[i];

  const float* hT = lds + HT_OFF;
  const float* wkT = lds + WK_OFF;
  const float* rnT = lds + RN_OFF;
  const float* b2T = lds + B2_OFF;
  const float* cfT = lds + CF_OFF;

  float qh[16], oa[16];
  {
    const float* qr = hT + sqv[L_SZ - 1] * ROW + s16;
    #pragma unroll
    for (int i = 0; i < 4; ++i) {
      const float4 q4 = *(const float4*)(qr + 4 * i);
      qh[4 * i + 0] = q4.x; qh[4 * i + 1] = q4.y; qh[4 * i + 2] = q4.z; qh[4 * i + 3] = q4.w;
    }
  }
  #pragma unroll
  for (int i = 0; i < 16; ++i) oa[i] = 0.0f;

  #pragma unroll
  for (int t = L_SZ - 2; t >= 0; --t) {
    const int tok = sqv[t];
    const float* kr = hT + tok * ROW + s16;
    float kv[16];
    #pragma unroll
    for (int i = 0; i < 4; ++i) {
      const float4 k4 = *(const float4*)(kr + 4 * i);
      kv[4 * i + 0] = k4.x; kv[4 * i + 1] = k4.y; kv[4 * i + 2] = k4.z; kv[4 * i + 3] = k4.w;
    }
    float p = 0.0f;
    #pragma unroll
    for (int i = 0; i < 16; ++i) p += kv[i] * qh[i];
    p += __shfl_xor(p, 1);
    p += __shfl_xor(p, 2);          // all 4 lanes of the quad now hold k.qhat

    const float rnv = rnT[tok];
    const float d = p * rnv;        // kn . qhat
    const float c = cfT[t] * d;     // (1 - a_t) * d
    const float u = c * rnv;

    #pragma unroll
    for (int i = 0; i < 16; ++i) qh[i] -= u * kv[i];

    const float* wr = wkT + tok * ROW + s16;
    #pragma unroll
    for (int i = 0; i < 4; ++i) {
      const float4 w4 = *(const float4*)(wr + 4 * i);
      oa[4 * i + 0] += c * w4.x; oa[4 * i + 1] += c * w4.y;
      oa[4 * i + 2] += c * w4.z; oa[4 * i + 3] += c * w4.w;
    }
  }

  #pragma unroll
  for (int i = 0; i < 16; ++i) oa[i] += b2T[s16 + i];

  float4* op = (float4*)(out + batch * V_SZ + s16);
  #pragma unroll
  for (int i = 0; i < 4; ++i)
    op[i] = make_float4(oa[4 * i + 0], oa[4 * i + 1], oa[4 * i + 2], oa[4 * i + 3]);
}

// ---------------------------------------------------------------------------
extern "C" void kernel_launch(void* const* d_in, const int* in_sizes, int n_in,
                              void* d_out, int out_size, void* d_ws, size_t ws_size,
                              hipStream_t stream)
{
  const int*   seq          = (const int*)d_in[0];
  const float* embed        = (const float*)d_in[1];
  const float* w1           = (const float*)d_in[2];
  const float* b1           = (const float*)d_in[3];
  const float* w2           = (const float*)d_in[4];
  const float* b2           = (const float*)d_in[5];
  const float* ln_g         = (const float*)d_in[6];
  const float* ln_b         = (const float*)d_in[7];
  const float* rp_w         = (const float*)d_in[8];
  const float* rp_b         = (const float*)d_in[9];
  const float* out_w        = (const float*)d_in[10];
  const float* out_b        = (const float*)d_in[11];
  const float* alpha_logits = (const float*)d_in[12];
  float* ws  = (float*)d_ws;
  float* outp = (float*)d_out;

  hipLaunchKernelGGL(k_tables, dim3(V_SZ), dim3(128), 0, stream,
                     embed, w1, b1, w2, b2, ln_g, ln_b, ws);
  hipLaunchKernelGGL(k_proj, dim3(V_SZ + 1), dim3(64), 0, stream,
                     rp_w, rp_b, out_w, out_b, alpha_logits, ws);
  hipLaunchKernelGGL(k_scan, dim3(B_SZ / 64), dim3(256), 0, stream,
                     seq, ws, outp);
}